// Round 21
// baseline (1689.529 us; speedup 1.0000x reference)
//
#include <hip/hip_runtime.h>

// WeightedRGCN on MI355X. Round 21: R20 (1485us) with the main kernel's
// fp32 VALU k-loop (63% VALUBusy, ~16 VALU ops / 8 FMA) replaced by MFMA on
// a block-shared A-tile. LDS stays 40KB (Bt 32KB + Atw 32x128 bf16 = 8KB)
// => 4 blocks/CU (R17's 66KB/2-block occupancy failure does not recur).
// 8 waves = 2 rowgroups x 4 colgroups; 8 MFMA/wave/phase; pieces R11-proven.
// CSR build = R20 verbatim.

#define N_USER 100000
#define N_POST 200000
#define DD 128
#define GU 3125            // 100000/32 rows per block
#define GP 6250            // 200000/32

typedef __attribute__((ext_vector_type(8))) short short8;
typedef __attribute__((ext_vector_type(4))) float floatx4;

__device__ __forceinline__ unsigned int pack2_bf16(float lo, float hi) {
    unsigned int ulo, uhi;
    __builtin_memcpy(&ulo, &lo, 4);
    __builtin_memcpy(&uhi, &hi, 4);
    unsigned int rlo = (ulo + 0x7fffu + ((ulo >> 16) & 1u)) >> 16;   // RNE
    unsigned int rhi = (uhi + 0x7fffu + ((uhi >> 16) & 1u)) >> 16;
    return (rlo & 0xffffu) | (rhi << 16);
}

// -------------------------------------------------- CSR build (R20 verbatim)
__global__ __launch_bounds__(256) void hist_all(
        const int* __restrict__ d0, int e0, int* __restrict__ c0,
        const int* __restrict__ d1, int e1, int* __restrict__ c1,
        const int* __restrict__ d2, int e2, int* __restrict__ c2,
        const int* __restrict__ d3, int e3, int* __restrict__ c3) {
    int i = blockIdx.x * 256 + threadIdx.x;
    int stride = gridDim.x * 256;
    int b1 = e0, b2 = e0 + e1, b3 = e0 + e1 + e2, tot = b3 + e3;
    for (int t = i; t < tot; t += stride) {
        if (t < b1)      atomicAdd(&c0[d0[t]], 1);
        else if (t < b2) atomicAdd(&c1[d1[t - b1]], 1);
        else if (t < b3) atomicAdd(&c2[d2[t - b2]], 1);
        else             atomicAdd(&c3[d3[t - b3]], 1);
    }
}

__global__ __launch_bounds__(256) void fill_all(
        const int* __restrict__ s0, const int* __restrict__ d0, int e0,
        const int* __restrict__ r0, int* __restrict__ w0, int* __restrict__ o0,
        const int* __restrict__ s1, const int* __restrict__ d1, int e1,
        const int* __restrict__ r1, int* __restrict__ w1, int* __restrict__ o1,
        const int* __restrict__ s2, const int* __restrict__ d2, int e2,
        const int* __restrict__ r2, int* __restrict__ w2, int* __restrict__ o2,
        const int* __restrict__ s3, const int* __restrict__ d3, int e3,
        const int* __restrict__ r3, int* __restrict__ w3, int* __restrict__ o3) {
    int i = blockIdx.x * 256 + threadIdx.x;
    int stride = gridDim.x * 256;
    int b1 = e0, b2 = e0 + e1, b3 = e0 + e1 + e2, tot = b3 + e3;
    for (int t = i; t < tot; t += stride) {
        if (t < b1)      { int e = t;      int d = d0[e]; o0[r0[d] + atomicAdd(&w0[d], 1)] = s0[e]; }
        else if (t < b2) { int e = t - b1; int d = d1[e]; o1[r1[d] + atomicAdd(&w1[d], 1)] = s1[e]; }
        else if (t < b3) { int e = t - b2; int d = d2[e]; o2[r2[d] + atomicAdd(&w2[d], 1)] = s2[e]; }
        else             { int e = t - b3; int d = d3[e]; o3[r3[d] + atomicAdd(&w3[d], 1)] = s3[e]; }
    }
}

#define SCB 256
#define SCE 16
#define SCCH (SCB * SCE)   // 4096
#define NBU 25
#define NBP 49

__device__ __forceinline__ void seg_map(int b, int* rp0, int* rp1, int* rp2,
                                        int* rp3, int* psum,
                                        int** a, int* N, int** ps, int* lb) {
    if (b < NBU)            { *a = rp0; *N = N_USER; *ps = psum;       *lb = b; }
    else if (b < 2 * NBU)   { *a = rp1; *N = N_USER; *ps = psum + 64;  *lb = b - NBU; }
    else if (b < 3 * NBU)   { *a = rp2; *N = N_USER; *ps = psum + 128; *lb = b - 2 * NBU; }
    else                    { *a = rp3; *N = N_POST; *ps = psum + 192; *lb = b - 3 * NBU; }
}

__global__ __launch_bounds__(SCB) void scan_partial_all(
        int* rp0, int* rp1, int* rp2, int* rp3, int* psum) {
    int* a; int N; int* ps; int lb;
    seg_map(blockIdx.x, rp0, rp1, rp2, rp3, psum, &a, &N, &ps, &lb);
    __shared__ int red[SCB];
    int tid = threadIdx.x;
    int i0 = lb * SCCH + tid * SCE;
    int s = 0;
#pragma unroll
    for (int j = 0; j < SCE; ++j) { int i = i0 + j; if (i < N) s += a[i]; }
    red[tid] = s;
    __syncthreads();
    for (int off = SCB / 2; off > 0; off >>= 1) {
        if (tid < off) red[tid] += red[tid + off];
        __syncthreads();
    }
    if (tid == 0) ps[lb] = red[0];
}

__global__ __launch_bounds__(1024) void scan_psum_all(int* __restrict__ psum) {
    __shared__ int t[1024];
    int tid = threadIdx.x;
    int nb = (blockIdx.x == 3) ? NBP : NBU;
    int* ps = psum + blockIdx.x * 64;
    int v = (tid < nb) ? ps[tid] : 0;
    t[tid] = v;
    __syncthreads();
    for (int off = 1; off < 1024; off <<= 1) {
        int u = (tid >= off) ? t[tid - off] : 0;
        __syncthreads();
        t[tid] += u;
        __syncthreads();
    }
    if (tid < nb) ps[tid] = t[tid] - v;   // exclusive
}

__global__ __launch_bounds__(SCB) void scan_final_all(
        int* rp0, int* rp1, int* rp2, int* rp3, int* psum,
        int E0, int E1, int E2, int E3) {
    int* a; int N; int* ps; int lb;
    seg_map(blockIdx.x, rp0, rp1, rp2, rp3, psum, &a, &N, &ps, &lb);
    int E = (blockIdx.x < NBU) ? E0 : (blockIdx.x < 2*NBU) ? E1
          : (blockIdx.x < 3*NBU) ? E2 : E3;
    __shared__ int red[SCB];
    int tid = threadIdx.x;
    int i0 = lb * SCCH + tid * SCE;
    int v[SCE];
    int s = 0;
#pragma unroll
    for (int j = 0; j < SCE; ++j) { int i = i0 + j; v[j] = (i < N) ? a[i] : 0; s += v[j]; }
    red[tid] = s;
    __syncthreads();
    for (int off = 1; off < SCB; off <<= 1) {   // inclusive Hillis-Steele
        int u = (tid >= off) ? red[tid - off] : 0;
        __syncthreads();
        red[tid] += u;
        __syncthreads();
    }
    int run = ps[lb] + red[tid] - s;
#pragma unroll
    for (int j = 0; j < SCE; ++j) { int i = i0 + j; if (i < N) a[i] = run; run += v[j]; }
    if (lb == 0 && tid == 0) a[N] = E;
}

// ------------------------------------------------------- MFMA pieces (R11) --
// Bt[col][k2] bf16x2 words, XOR-swizzled: Bt[c*64 + (k2 ^ ((c&7)<<2))]
__device__ __forceinline__ void stage_Bt_one(const float* __restrict__ W,
                                             unsigned int* Bt, int tid) {
    for (int idx = tid; idx < 128 * 64; idx += 512) {
        int c = idx & 127, k2 = idx >> 7;
        float lo = W[(2 * k2) * 128 + c];
        float hi = W[(2 * k2 + 1) * 128 + c];
        Bt[c * 64 + (k2 ^ ((c & 7) << 2))] = pack2_bf16(lo, hi);
    }
}
__device__ __forceinline__ void stage_Bt_comb(const float* __restrict__ W0,
                                              const float* __restrict__ W1,
                                              const float* __restrict__ W2,
                                              unsigned int* Bt, int tid) {
    for (int idx = tid; idx < 128 * 64; idx += 512) {
        int c = idx & 127, k2 = idx >> 7;
        int e0 = (2 * k2) * 128 + c, e1 = (2 * k2 + 1) * 128 + c;
        float lo = 1.75f * W0[e0] + 0.7f * W1[e0] + 0.3f * W2[e0];
        float hi = 1.75f * W0[e1] + 0.7f * W1[e1] + 0.3f * W2[e1];
        Bt[c * 64 + (k2 ^ ((c & 7) << 2))] = pack2_bf16(lo, hi);
    }
}

// dense 4 rows (this wave's) -> shared A-tile (bf16x2 words, R11 layout:
// word kk=lane holds features 2*lane,2*lane+1; XOR row swizzle)
__device__ __forceinline__ void dense_rows(const float* __restrict__ x,
                                           int gbase, int N, int wave, int lane,
                                           unsigned int* Atw) {
#pragma unroll
    for (int i = 0; i < 4; ++i) {
        int r = wave * 4 + i;          // local row 0..31
        int row = gbase + i;
        float vx = 0.f, vy = 0.f;
        if (row < N) {
            float2 v = ((const float2*)(x + (size_t)row * DD))[lane];
            vx = v.x; vy = v.y;
        }
        Atw[r * 64 + (lane ^ ((r & 7) << 2))] = pack2_bf16(vx, vy);
    }
}

// CSR-mean 4 rows (R16-proven interleave) -> shared A-tile (R11 layout)
__device__ __forceinline__ void gather_rows(const float* __restrict__ x,
                                            const int* __restrict__ rp,
                                            const int* __restrict__ col, float scale,
                                            int gbase, int N, int wave, int lane,
                                            unsigned int* Atw) {
    int s0[4], dg[4];
    int maxd = 0;
#pragma unroll
    for (int i = 0; i < 4; ++i) {
        int row = gbase + i;
        int e0 = (row < N) ? rp[row] : 0;
        int e1 = (row < N) ? rp[row + 1] : 0;
        s0[i] = e0;
        dg[i] = e1 - e0;
        maxd = max(maxd, dg[i]);
    }
    float a0[4] = {0.f, 0.f, 0.f, 0.f};
    float a1[4] = {0.f, 0.f, 0.f, 0.f};
#pragma unroll 2
    for (int d = 0; d < maxd; ++d) {
#pragma unroll
        for (int i = 0; i < 4; ++i) {
            if (d < dg[i]) {
                const float2* xr = (const float2*)(x + (size_t)col[s0[i] + d] * DD);
                float2 v = xr[lane];
                a0[i] += v.x;
                a1[i] += v.y;
            }
        }
    }
#pragma unroll
    for (int i = 0; i < 4; ++i) {
        int r = wave * 4 + i;
        float inv = scale / fmaxf((float)dg[i], 1.0f);
        Atw[r * 64 + (lane ^ ((r & 7) << 2))] = pack2_bf16(a0[i] * inv, a1[i] * inv);
    }
}

// 8 MFMA per wave: rowgroup rg (16 rows), colgroup cg (2x16 cols), K=128
__device__ __forceinline__ void kloop_mfma32(const unsigned int* Atw,
                                             const unsigned int* Bt,
                                             int lane, int rg, int cg,
                                             floatx4 acc[2]) {
    int r16 = lane & 15, h = lane >> 4;
    int sw = (r16 & 7) << 4;
#pragma unroll
    for (int ks = 0; ks < 4; ++ks) {
        int off = (ks * 64 + h * 16) ^ sw;
        short8 a = *(const short8*)((const char*)Atw + (rg * 16 + r16) * 256 + off);
#pragma unroll
        for (int ct = 0; ct < 2; ++ct) {
            short8 b = *(const short8*)(
                (const char*)Bt + (cg * 32 + ct * 16 + r16) * 256 + off);
            acc[ct] = __builtin_amdgcn_mfma_f32_16x16x32_bf16(a, b, acc[ct], 0, 0, 0);
        }
    }
}

// --------------------------------------------------------- fused main bodies
__device__ void user_body(
        int blk, const float* __restrict__ xu, const float* __restrict__ xp,
        const int* __restrict__ rp_re, const int* __restrict__ col_re,
        const int* __restrict__ rp_fb, const int* __restrict__ col_fb,
        const int* __restrict__ rp_soc, const int* __restrict__ col_soc,
        const float* __restrict__ Wl_d, const float* __restrict__ Wl_a,
        const float* __restrict__ Wl_s, const float* __restrict__ WrD,
        const float* __restrict__ WrA, const float* __restrict__ WrS,
        const float* __restrict__ bD, const float* __restrict__ bA,
        const float* __restrict__ bS, float* __restrict__ out,
        unsigned int* Bt, unsigned int* Atw) {
    int tid = threadIdx.x, wave = tid >> 6, lane = tid & 63;
    int rg = wave >> 2, cg = wave & 3;
    int gbase = blk * 32 + wave * 4;
    floatx4 zz = {0.f, 0.f, 0.f, 0.f};
    floatx4 acc[2] = {zz, zz};
    // phase 1: re (post -> user), 1.75
    stage_Bt_one(Wl_d, Bt, tid);
    gather_rows(xp, rp_re, col_re, 1.75f, gbase, N_USER, wave, lane, Atw);
    __syncthreads();
    kloop_mfma32(Atw, Bt, lane, rg, cg, acc);
    __syncthreads();
    // phase 2: fb (post -> user), 0.7
    stage_Bt_one(Wl_a, Bt, tid);
    gather_rows(xp, rp_fb, col_fb, 0.7f, gbase, N_USER, wave, lane, Atw);
    __syncthreads();
    kloop_mfma32(Atw, Bt, lane, rg, cg, acc);
    __syncthreads();
    // phase 3: soc (user -> user), 0.3
    stage_Bt_one(Wl_s, Bt, tid);
    gather_rows(xu, rp_soc, col_soc, 0.3f, gbase, N_USER, wave, lane, Atw);
    __syncthreads();
    kloop_mfma32(Atw, Bt, lane, rg, cg, acc);
    __syncthreads();
    // phase 4: dense xu @ combined Wr
    stage_Bt_comb(WrD, WrA, WrS, Bt, tid);
    dense_rows(xu, gbase, N_USER, wave, lane, Atw);
    __syncthreads();
    kloop_mfma32(Atw, Bt, lane, rg, cg, acc);
    // epilogue (C layout m89: col=lane&15 tile-col, row=(lane>>4)*4+reg)
    int r16 = lane & 15, h = lane >> 4;
#pragma unroll
    for (int ct = 0; ct < 2; ++ct) {
        int c = cg * 32 + ct * 16 + r16;
        float bc = 1.75f * bD[c] + 0.7f * bA[c] + 0.3f * bS[c];
#pragma unroll
        for (int r = 0; r < 4; ++r) {
            int row = blk * 32 + rg * 16 + h * 4 + r;
            if (row < N_USER)
                out[(size_t)row * DD + c] = fmaxf(acc[ct][r] + bc, 0.f);
        }
    }
}

__device__ void post_body(
        int blk, const float* __restrict__ xu, const int* __restrict__ rp,
        const int* __restrict__ col, const float* __restrict__ xp,
        const float* __restrict__ Wl, const float* __restrict__ Wr,
        const float* __restrict__ bias, float* __restrict__ out,
        unsigned int* Bt, unsigned int* Atw) {
    int tid = threadIdx.x, wave = tid >> 6, lane = tid & 63;
    int rg = wave >> 2, cg = wave & 3;
    int gbase = blk * 32 + wave * 4;
    floatx4 zz = {0.f, 0.f, 0.f, 0.f};
    floatx4 acc[2] = {zz, zz};
    // pass 1: gather(eng) @ Wl
    stage_Bt_one(Wl, Bt, tid);
    gather_rows(xu, rp, col, 1.0f, gbase, N_POST, wave, lane, Atw);
    __syncthreads();
    kloop_mfma32(Atw, Bt, lane, rg, cg, acc);
    __syncthreads();
    // pass 2: dense xp @ Wr
    stage_Bt_one(Wr, Bt, tid);
    dense_rows(xp, gbase, N_POST, wave, lane, Atw);
    __syncthreads();
    kloop_mfma32(Atw, Bt, lane, rg, cg, acc);
    int r16 = lane & 15, h = lane >> 4;
#pragma unroll
    for (int ct = 0; ct < 2; ++ct) {
        int c = cg * 32 + ct * 16 + r16;
        float bc = bias[c];
#pragma unroll
        for (int r = 0; r < 4; ++r) {
            int row = blk * 32 + rg * 16 + h * 4 + r;
            if (row < N_POST)
                out[(size_t)row * DD + c] = fmaxf(acc[ct][r] + bc, 0.f);
        }
    }
}

// user blocks [0, GU), post blocks [GU, GU+GP)
__global__ __launch_bounds__(512) void main_fused_kernel(
        const float* __restrict__ xu, const float* __restrict__ xp,
        const int* __restrict__ rp_re, const int* __restrict__ col_re,
        const int* __restrict__ rp_fb, const int* __restrict__ col_fb,
        const int* __restrict__ rp_soc, const int* __restrict__ col_soc,
        const int* __restrict__ rp_post, const int* __restrict__ col_post,
        const float* __restrict__ Wl_d, const float* __restrict__ Wl_a,
        const float* __restrict__ Wl_s, const float* __restrict__ WrD,
        const float* __restrict__ WrA, const float* __restrict__ WrS,
        const float* __restrict__ bD, const float* __restrict__ bA,
        const float* __restrict__ bS, const float* __restrict__ Wl_p,
        const float* __restrict__ Wr_p, const float* __restrict__ bl_p,
        float* __restrict__ out_user, float* __restrict__ out_post) {
    __shared__ unsigned int Bt[128 * 64];    // 32 KB
    __shared__ unsigned int Atw[32 * 64];    // 8 KB -> 40 KB total, 4 blk/CU
    if (blockIdx.x < GU) {
        user_body(blockIdx.x, xu, xp, rp_re, col_re, rp_fb, col_fb,
                  rp_soc, col_soc, Wl_d, Wl_a, Wl_s, WrD, WrA, WrS,
                  bD, bA, bS, out_user, Bt, Atw);
    } else {
        post_body(blockIdx.x - GU, xu, rp_post, col_post, xp,
                  Wl_p, Wr_p, bl_p, out_post, Bt, Atw);
    }
}

// ------------------------------------------------------------------ launch --
extern "C" void kernel_launch(void* const* d_in, const int* in_sizes, int n_in,
                              void* d_out, int out_size, void* d_ws, size_t ws_size,
                              hipStream_t stream) {
    const float* x_user  = (const float*)d_in[0];
    const float* x_post  = (const float*)d_in[1];
    const int*   re_src  = (const int*)d_in[2];
    const int*   re_dst  = (const int*)d_in[3];
    const int*   fb_src  = (const int*)d_in[4];
    const int*   fb_dst  = (const int*)d_in[5];
    const int*   soc_src = (const int*)d_in[6];
    const int*   soc_dst = (const int*)d_in[7];
    const int*   eng_src = (const int*)d_in[8];
    const int*   eng_dst = (const int*)d_in[9];
    const float* Wl_d = (const float*)d_in[10];
    const float* bl_d = (const float*)d_in[11];
    const float* Wr_d = (const float*)d_in[12];
    const float* Wl_a = (const float*)d_in[13];
    const float* bl_a = (const float*)d_in[14];
    const float* Wr_a = (const float*)d_in[15];
    const float* Wl_s = (const float*)d_in[16];
    const float* bl_s = (const float*)d_in[17];
    const float* Wr_s = (const float*)d_in[18];
    const float* Wl_p = (const float*)d_in[19];
    const float* bl_p = (const float*)d_in[20];
    const float* Wr_p = (const float*)d_in[21];

    const int E_re  = in_sizes[2];
    const int E_fb  = in_sizes[4];
    const int E_soc = in_sizes[6];
    const int E_eng = in_sizes[8];

    int* ib = (int*)d_ws;
    int* rp_re    = ib;
    int* rp_fb    = rp_re   + (N_USER + 1);
    int* rp_soc   = rp_fb   + (N_USER + 1);
    int* rp_post  = rp_soc  + (N_USER + 1);
    int* wcur_re  = rp_post + (N_POST + 1);
    int* wcur_fb  = wcur_re + N_USER;
    int* wcur_soc = wcur_fb + N_USER;
    int* wcur_post= wcur_soc+ N_USER;
    int* psum     = wcur_post + N_POST;      // 4 x 64 slices
    int* col_re   = psum + 256;
    int* col_fb   = col_re  + E_re;
    int* col_soc  = col_fb  + E_fb;
    int* col_post = col_soc + E_soc;

    float* out_user = (float*)d_out;
    float* out_post = out_user + (size_t)N_USER * DD;

    // one memset over rp + wcur + psum (contiguous)
    size_t zero_ints = (size_t)(N_USER + 1) * 3 + (N_POST + 1)
                     + (size_t)N_USER * 3 + N_POST + 256;
    hipMemsetAsync(rp_re, 0, zero_ints * sizeof(int), stream);

    hist_all<<<2048, 256, 0, stream>>>(re_dst, E_re, rp_re,
                                       fb_dst, E_fb, rp_fb,
                                       soc_dst, E_soc, rp_soc,
                                       eng_dst, E_eng, rp_post);

    const int SC_BLOCKS_ALL = 3 * NBU + NBP;   // 124
    scan_partial_all<<<SC_BLOCKS_ALL, SCB, 0, stream>>>(rp_re, rp_fb, rp_soc,
                                                        rp_post, psum);
    scan_psum_all<<<4, 1024, 0, stream>>>(psum);
    scan_final_all<<<SC_BLOCKS_ALL, SCB, 0, stream>>>(rp_re, rp_fb, rp_soc,
                                                      rp_post, psum,
                                                      E_re, E_fb, E_soc, E_eng);

    fill_all<<<2048, 256, 0, stream>>>(
        re_src,  re_dst,  E_re,  rp_re,   wcur_re,   col_re,
        fb_src,  fb_dst,  E_fb,  rp_fb,   wcur_fb,   col_fb,
        soc_src, soc_dst, E_soc, rp_soc,  wcur_soc,  col_soc,
        eng_src, eng_dst, E_eng, rp_post, wcur_post, col_post);

    main_fused_kernel<<<GU + GP, 512, 0, stream>>>(
        x_user, x_post, rp_re, col_re, rp_fb, col_fb, rp_soc, col_soc,
        rp_post, col_post, Wl_d, Wl_a, Wl_s, Wr_d, Wr_a, Wr_s,
        bl_d, bl_a, bl_s, Wl_p, Wr_p, bl_p, out_user, out_post);
}

// Round 22
// 1324.081 us; speedup vs baseline: 1.2760x; 1.2760x over previous
//
#include <hip/hip_runtime.h>

// WeightedRGCN on MI355X. Round 22: revert R21's MFMA (3rd MFMA regression:
// 28.8M LDS conflicts, occ 46%). Base = R20 (1485us, fp32 kloop, 40KB LDS,
// 4 blk/CU, 0 conflicts) with the kloop switched to v_dot2_f32_bf16 on
// k-pair-packed tiles: Bt[k2][c]=(B[2k2][c],B[2k2+1][c]),
// Atw[k2][r] = gather's (feat 2*lane, feat 2*lane+1) = k-pair at k2=lane.
// Per k2: 1 broadcast b128 + 2 b32 + 8 dot2 = 32 FLOP in ~11 instr (was ~32).
// CSR build = R20 verbatim. Accumulation fp32 -> absmax unchanged 0.0625.

#define N_USER 100000
#define N_POST 200000
#define DD 128
#define GU 3125            // 100000/32 rows per block
#define GP 6250            // 200000/32

__device__ __forceinline__ unsigned int pack2_bf16(float lo, float hi) {
    unsigned int ulo, uhi;
    __builtin_memcpy(&ulo, &lo, 4);
    __builtin_memcpy(&uhi, &hi, 4);
    unsigned int rlo = (ulo + 0x7fffu + ((ulo >> 16) & 1u)) >> 16;   // RNE
    unsigned int rhi = (uhi + 0x7fffu + ((uhi >> 16) & 1u)) >> 16;
    return (rlo & 0xffffu) | (rhi << 16);
}

// D = a.lo*b.lo + a.hi*b.hi + c   (packed bf16 dot-2, fp32 accumulate)
__device__ __forceinline__ float dot2_bf16(unsigned int a, unsigned int b, float c) {
    float r;
    asm("v_dot2_f32_bf16 %0, %1, %2, %3" : "=v"(r) : "v"(a), "v"(b), "v"(c));
    return r;
}

// -------------------------------------------------- CSR build (R20 verbatim)
__global__ __launch_bounds__(256) void hist_all(
        const int* __restrict__ d0, int e0, int* __restrict__ c0,
        const int* __restrict__ d1, int e1, int* __restrict__ c1,
        const int* __restrict__ d2, int e2, int* __restrict__ c2,
        const int* __restrict__ d3, int e3, int* __restrict__ c3) {
    int i = blockIdx.x * 256 + threadIdx.x;
    int stride = gridDim.x * 256;
    int b1 = e0, b2 = e0 + e1, b3 = e0 + e1 + e2, tot = b3 + e3;
    for (int t = i; t < tot; t += stride) {
        if (t < b1)      atomicAdd(&c0[d0[t]], 1);
        else if (t < b2) atomicAdd(&c1[d1[t - b1]], 1);
        else if (t < b3) atomicAdd(&c2[d2[t - b2]], 1);
        else             atomicAdd(&c3[d3[t - b3]], 1);
    }
}

__global__ __launch_bounds__(256) void fill_all(
        const int* __restrict__ s0, const int* __restrict__ d0, int e0,
        const int* __restrict__ r0, int* __restrict__ w0, int* __restrict__ o0,
        const int* __restrict__ s1, const int* __restrict__ d1, int e1,
        const int* __restrict__ r1, int* __restrict__ w1, int* __restrict__ o1,
        const int* __restrict__ s2, const int* __restrict__ d2, int e2,
        const int* __restrict__ r2, int* __restrict__ w2, int* __restrict__ o2,
        const int* __restrict__ s3, const int* __restrict__ d3, int e3,
        const int* __restrict__ r3, int* __restrict__ w3, int* __restrict__ o3) {
    int i = blockIdx.x * 256 + threadIdx.x;
    int stride = gridDim.x * 256;
    int b1 = e0, b2 = e0 + e1, b3 = e0 + e1 + e2, tot = b3 + e3;
    for (int t = i; t < tot; t += stride) {
        if (t < b1)      { int e = t;      int d = d0[e]; o0[r0[d] + atomicAdd(&w0[d], 1)] = s0[e]; }
        else if (t < b2) { int e = t - b1; int d = d1[e]; o1[r1[d] + atomicAdd(&w1[d], 1)] = s1[e]; }
        else if (t < b3) { int e = t - b2; int d = d2[e]; o2[r2[d] + atomicAdd(&w2[d], 1)] = s2[e]; }
        else             { int e = t - b3; int d = d3[e]; o3[r3[d] + atomicAdd(&w3[d], 1)] = s3[e]; }
    }
}

#define SCB 256
#define SCE 16
#define SCCH (SCB * SCE)   // 4096
#define NBU 25
#define NBP 49

__device__ __forceinline__ void seg_map(int b, int* rp0, int* rp1, int* rp2,
                                        int* rp3, int* psum,
                                        int** a, int* N, int** ps, int* lb) {
    if (b < NBU)            { *a = rp0; *N = N_USER; *ps = psum;       *lb = b; }
    else if (b < 2 * NBU)   { *a = rp1; *N = N_USER; *ps = psum + 64;  *lb = b - NBU; }
    else if (b < 3 * NBU)   { *a = rp2; *N = N_USER; *ps = psum + 128; *lb = b - 2 * NBU; }
    else                    { *a = rp3; *N = N_POST; *ps = psum + 192; *lb = b - 3 * NBU; }
}

__global__ __launch_bounds__(SCB) void scan_partial_all(
        int* rp0, int* rp1, int* rp2, int* rp3, int* psum) {
    int* a; int N; int* ps; int lb;
    seg_map(blockIdx.x, rp0, rp1, rp2, rp3, psum, &a, &N, &ps, &lb);
    __shared__ int red[SCB];
    int tid = threadIdx.x;
    int i0 = lb * SCCH + tid * SCE;
    int s = 0;
#pragma unroll
    for (int j = 0; j < SCE; ++j) { int i = i0 + j; if (i < N) s += a[i]; }
    red[tid] = s;
    __syncthreads();
    for (int off = SCB / 2; off > 0; off >>= 1) {
        if (tid < off) red[tid] += red[tid + off];
        __syncthreads();
    }
    if (tid == 0) ps[lb] = red[0];
}

__global__ __launch_bounds__(1024) void scan_psum_all(int* __restrict__ psum) {
    __shared__ int t[1024];
    int tid = threadIdx.x;
    int nb = (blockIdx.x == 3) ? NBP : NBU;
    int* ps = psum + blockIdx.x * 64;
    int v = (tid < nb) ? ps[tid] : 0;
    t[tid] = v;
    __syncthreads();
    for (int off = 1; off < 1024; off <<= 1) {
        int u = (tid >= off) ? t[tid - off] : 0;
        __syncthreads();
        t[tid] += u;
        __syncthreads();
    }
    if (tid < nb) ps[tid] = t[tid] - v;   // exclusive
}

__global__ __launch_bounds__(SCB) void scan_final_all(
        int* rp0, int* rp1, int* rp2, int* rp3, int* psum,
        int E0, int E1, int E2, int E3) {
    int* a; int N; int* ps; int lb;
    seg_map(blockIdx.x, rp0, rp1, rp2, rp3, psum, &a, &N, &ps, &lb);
    int E = (blockIdx.x < NBU) ? E0 : (blockIdx.x < 2*NBU) ? E1
          : (blockIdx.x < 3*NBU) ? E2 : E3;
    __shared__ int red[SCB];
    int tid = threadIdx.x;
    int i0 = lb * SCCH + tid * SCE;
    int v[SCE];
    int s = 0;
#pragma unroll
    for (int j = 0; j < SCE; ++j) { int i = i0 + j; v[j] = (i < N) ? a[i] : 0; s += v[j]; }
    red[tid] = s;
    __syncthreads();
    for (int off = 1; off < SCB; off <<= 1) {   // inclusive Hillis-Steele
        int u = (tid >= off) ? red[tid - off] : 0;
        __syncthreads();
        red[tid] += u;
        __syncthreads();
    }
    int run = ps[lb] + red[tid] - s;
#pragma unroll
    for (int j = 0; j < SCE; ++j) { int i = i0 + j; if (i < N) a[i] = run; run += v[j]; }
    if (lb == 0 && tid == 0) a[N] = E;
}

// ------------------------------------------------------------ GEMM pieces ---
// Bt[k2][c] = (B[2k2][c], B[2k2+1][c])  -- k-pair packed, 64x128 words = 32KB
__device__ __forceinline__ void stage_Bt(const float* __restrict__ B,
                                         unsigned int* Bt, int tid) {
    for (int idx = tid; idx < 64 * 128; idx += 512) {
        int k2 = idx >> 7, c = idx & 127;
        Bt[idx] = pack2_bf16(B[(2 * k2) * 128 + c], B[(2 * k2 + 1) * 128 + c]);
    }
}
__device__ __forceinline__ void stage_Bt_comb(const float* __restrict__ W0,
                                              const float* __restrict__ W1,
                                              const float* __restrict__ W2,
                                              unsigned int* Bt, int tid) {
    for (int idx = tid; idx < 64 * 128; idx += 512) {
        int k2 = idx >> 7, c = idx & 127;
        int e0 = (2 * k2) * 128 + c, e1 = (2 * k2 + 1) * 128 + c;
        float lo = 1.75f * W0[e0] + 0.7f * W1[e0] + 0.3f * W2[e0];
        float hi = 1.75f * W0[e1] + 0.7f * W1[e1] + 0.3f * W2[e1];
        Bt[idx] = pack2_bf16(lo, hi);
    }
}

// dense 4 rows -> per-wave A tile Atw[k2][r]: word = (feat 2k2, feat 2k2+1)
// of row r; lane handles k2=lane (float2 load gives exactly that pair).
__device__ __forceinline__ void load_rows(const float* __restrict__ A,
                                          int base, int N, int lane,
                                          unsigned int* atw) {
    uint4 w;
    unsigned int* wp = (unsigned int*)&w;
#pragma unroll
    for (int i = 0; i < 4; ++i) {
        int row = base + i;
        float vx = 0.f, vy = 0.f;
        if (row < N) {
            float2 v = ((const float2*)(A + (size_t)row * DD))[lane];
            vx = v.x; vy = v.y;
        }
        wp[i] = pack2_bf16(vx, vy);
    }
    *reinterpret_cast<uint4*>(atw + 4 * lane) = w;   // Atw[k2=lane][0..3]
}

// CSR-mean 4 rows (R16-proven interleave) -> Atw[k2=lane][r]
__device__ __forceinline__ void gather_rows(const float* __restrict__ x,
                                            const int* __restrict__ rp,
                                            const int* __restrict__ col, float scale,
                                            int base, int N, int lane,
                                            unsigned int* atw) {
    int s0[4], dg[4];
    int maxd = 0;
#pragma unroll
    for (int i = 0; i < 4; ++i) {
        int row = base + i;
        int e0 = (row < N) ? rp[row] : 0;
        int e1 = (row < N) ? rp[row + 1] : 0;
        s0[i] = e0;
        dg[i] = e1 - e0;
        maxd = max(maxd, dg[i]);
    }
    float a0[4] = {0.f, 0.f, 0.f, 0.f};
    float a1[4] = {0.f, 0.f, 0.f, 0.f};
#pragma unroll 2
    for (int d = 0; d < maxd; ++d) {
#pragma unroll
        for (int i = 0; i < 4; ++i) {
            if (d < dg[i]) {
                const float2* xr = (const float2*)(x + (size_t)col[s0[i] + d] * DD);
                float2 v = xr[lane];
                a0[i] += v.x;
                a1[i] += v.y;
            }
        }
    }
    uint4 w;
    unsigned int* wp = (unsigned int*)&w;
#pragma unroll
    for (int i = 0; i < 4; ++i) {
        float inv = scale / fmaxf((float)dg[i], 1.0f);
        wp[i] = pack2_bf16(a0[i] * inv, a1[i] * inv);
    }
    *reinterpret_cast<uint4*>(atw + 4 * lane) = w;
}

// per k2: 1 broadcast b128 (A rows 0..3) + 2 b32 (B cols lane, lane+64)
// + 8 dot2. acc[i][0]=col lane, acc[i][1]=col lane+64 (same as R20).
__device__ __forceinline__ void kloop_dot2(const unsigned int* atw,
                                           const unsigned int* Bt,
                                           int lane, float acc[4][2]) {
#pragma unroll 4
    for (int k2 = 0; k2 < 64; ++k2) {
        uint4 aw = *reinterpret_cast<const uint4*>(atw + k2 * 4);   // broadcast
        unsigned int b0 = Bt[k2 * 128 + lane];
        unsigned int b1 = Bt[k2 * 128 + 64 + lane];
        acc[0][0] = dot2_bf16(aw.x, b0, acc[0][0]);
        acc[0][1] = dot2_bf16(aw.x, b1, acc[0][1]);
        acc[1][0] = dot2_bf16(aw.y, b0, acc[1][0]);
        acc[1][1] = dot2_bf16(aw.y, b1, acc[1][1]);
        acc[2][0] = dot2_bf16(aw.z, b0, acc[2][0]);
        acc[2][1] = dot2_bf16(aw.z, b1, acc[2][1]);
        acc[3][0] = dot2_bf16(aw.w, b0, acc[3][0]);
        acc[3][1] = dot2_bf16(aw.w, b1, acc[3][1]);
    }
}

// --------------------------------------------------------- fused main bodies
__device__ void user_body(
        int blk, const float* __restrict__ xu, const float* __restrict__ xp,
        const int* __restrict__ rp_re, const int* __restrict__ col_re,
        const int* __restrict__ rp_fb, const int* __restrict__ col_fb,
        const int* __restrict__ rp_soc, const int* __restrict__ col_soc,
        const float* __restrict__ Wl_d, const float* __restrict__ Wl_a,
        const float* __restrict__ Wl_s, const float* __restrict__ WrD,
        const float* __restrict__ WrA, const float* __restrict__ WrS,
        const float* __restrict__ bD, const float* __restrict__ bA,
        const float* __restrict__ bS, float* __restrict__ out,
        unsigned int* Bt, unsigned int (*Atw)[256]) {
    int wave = threadIdx.x >> 6, lane = threadIdx.x & 63;
    int base = (blk * 8 + wave) * 4;
    float acc[4][2] = {{0.f,0.f},{0.f,0.f},{0.f,0.f},{0.f,0.f}};
    stage_Bt(Wl_d, Bt, threadIdx.x);
    __syncthreads();
    gather_rows(xp, rp_re, col_re, 1.75f, base, N_USER, lane, Atw[wave]);
    kloop_dot2(Atw[wave], Bt, lane, acc);
    __syncthreads();
    stage_Bt(Wl_a, Bt, threadIdx.x);
    __syncthreads();
    gather_rows(xp, rp_fb, col_fb, 0.7f, base, N_USER, lane, Atw[wave]);
    kloop_dot2(Atw[wave], Bt, lane, acc);
    __syncthreads();
    stage_Bt(Wl_s, Bt, threadIdx.x);
    __syncthreads();
    gather_rows(xu, rp_soc, col_soc, 0.3f, base, N_USER, lane, Atw[wave]);
    kloop_dot2(Atw[wave], Bt, lane, acc);
    __syncthreads();
    stage_Bt_comb(WrD, WrA, WrS, Bt, threadIdx.x);
    __syncthreads();
    load_rows(xu, base, N_USER, lane, Atw[wave]);
    kloop_dot2(Atw[wave], Bt, lane, acc);
    float bc0 = 1.75f*bD[lane]    + 0.7f*bA[lane]    + 0.3f*bS[lane];
    float bc1 = 1.75f*bD[lane+64] + 0.7f*bA[lane+64] + 0.3f*bS[lane+64];
#pragma unroll
    for (int i = 0; i < 4; ++i) {
        int row = base + i;
        if (row < N_USER) {
            out[(size_t)row * DD + lane]      = fmaxf(acc[i][0] + bc0, 0.f);
            out[(size_t)row * DD + lane + 64] = fmaxf(acc[i][1] + bc1, 0.f);
        }
    }
}

__device__ void post_body(
        int blk, const float* __restrict__ xu, const int* __restrict__ rp,
        const int* __restrict__ col, const float* __restrict__ xp,
        const float* __restrict__ Wl, const float* __restrict__ Wr,
        const float* __restrict__ bias, float* __restrict__ out,
        unsigned int* Bt, unsigned int (*Atw)[256]) {
    int wave = threadIdx.x >> 6, lane = threadIdx.x & 63;
    int base = (blk * 8 + wave) * 4;
    float acc[4][2] = {{0.f,0.f},{0.f,0.f},{0.f,0.f},{0.f,0.f}};
    stage_Bt(Wl, Bt, threadIdx.x);
    __syncthreads();
    gather_rows(xu, rp, col, 1.0f, base, N_POST, lane, Atw[wave]);
    kloop_dot2(Atw[wave], Bt, lane, acc);
    __syncthreads();
    stage_Bt(Wr, Bt, threadIdx.x);
    __syncthreads();
    load_rows(xp, base, N_POST, lane, Atw[wave]);
    kloop_dot2(Atw[wave], Bt, lane, acc);
    float b0 = bias[lane], b1 = bias[lane + 64];
#pragma unroll
    for (int i = 0; i < 4; ++i) {
        int row = base + i;
        if (row < N_POST) {
            out[(size_t)row * DD + lane]      = fmaxf(acc[i][0] + b0, 0.f);
            out[(size_t)row * DD + lane + 64] = fmaxf(acc[i][1] + b1, 0.f);
        }
    }
}

// user blocks [0, GU), post blocks [GU, GU+GP)
__global__ __launch_bounds__(512) void main_fused_kernel(
        const float* __restrict__ xu, const float* __restrict__ xp,
        const int* __restrict__ rp_re, const int* __restrict__ col_re,
        const int* __restrict__ rp_fb, const int* __restrict__ col_fb,
        const int* __restrict__ rp_soc, const int* __restrict__ col_soc,
        const int* __restrict__ rp_post, const int* __restrict__ col_post,
        const float* __restrict__ Wl_d, const float* __restrict__ Wl_a,
        const float* __restrict__ Wl_s, const float* __restrict__ WrD,
        const float* __restrict__ WrA, const float* __restrict__ WrS,
        const float* __restrict__ bD, const float* __restrict__ bA,
        const float* __restrict__ bS, const float* __restrict__ Wl_p,
        const float* __restrict__ Wr_p, const float* __restrict__ bl_p,
        float* __restrict__ out_user, float* __restrict__ out_post) {
    __shared__ unsigned int Bt[64 * 128];        // 32 KB
    __shared__ unsigned int Atw[8][256];         // 8 KB -> 40 KB, 4 blk/CU
    if (blockIdx.x < GU) {
        user_body(blockIdx.x, xu, xp, rp_re, col_re, rp_fb, col_fb,
                  rp_soc, col_soc, Wl_d, Wl_a, Wl_s, WrD, WrA, WrS,
                  bD, bA, bS, out_user, Bt, Atw);
    } else {
        post_body(blockIdx.x - GU, xu, rp_post, col_post, xp,
                  Wl_p, Wr_p, bl_p, out_post, Bt, Atw);
    }
}

// ------------------------------------------------------------------ launch --
extern "C" void kernel_launch(void* const* d_in, const int* in_sizes, int n_in,
                              void* d_out, int out_size, void* d_ws, size_t ws_size,
                              hipStream_t stream) {
    const float* x_user  = (const float*)d_in[0];
    const float* x_post  = (const float*)d_in[1];
    const int*   re_src  = (const int*)d_in[2];
    const int*   re_dst  = (const int*)d_in[3];
    const int*   fb_src  = (const int*)d_in[4];
    const int*   fb_dst  = (const int*)d_in[5];
    const int*   soc_src = (const int*)d_in[6];
    const int*   soc_dst = (const int*)d_in[7];
    const int*   eng_src = (const int*)d_in[8];
    const int*   eng_dst = (const int*)d_in[9];
    const float* Wl_d = (const float*)d_in[10];
    const float* bl_d = (const float*)d_in[11];
    const float* Wr_d = (const float*)d_in[12];
    const float* Wl_a = (const float*)d_in[13];
    const float* bl_a = (const float*)d_in[14];
    const float* Wr_a = (const float*)d_in[15];
    const float* Wl_s = (const float*)d_in[16];
    const float* bl_s = (const float*)d_in[17];
    const float* Wr_s = (const float*)d_in[18];
    const float* Wl_p = (const float*)d_in[19];
    const float* bl_p = (const float*)d_in[20];
    const float* Wr_p = (const float*)d_in[21];

    const int E_re  = in_sizes[2];
    const int E_fb  = in_sizes[4];
    const int E_soc = in_sizes[6];
    const int E_eng = in_sizes[8];

    int* ib = (int*)d_ws;
    int* rp_re    = ib;
    int* rp_fb    = rp_re   + (N_USER + 1);
    int* rp_soc   = rp_fb   + (N_USER + 1);
    int* rp_post  = rp_soc  + (N_USER + 1);
    int* wcur_re  = rp_post + (N_POST + 1);
    int* wcur_fb  = wcur_re + N_USER;
    int* wcur_soc = wcur_fb + N_USER;
    int* wcur_post= wcur_soc+ N_USER;
    int* psum     = wcur_post + N_POST;      // 4 x 64 slices
    int* col_re   = psum + 256;
    int* col_fb   = col_re  + E_re;
    int* col_soc  = col_fb  + E_fb;
    int* col_post = col_soc + E_soc;

    float* out_user = (float*)d_out;
    float* out_post = out_user + (size_t)N_USER * DD;

    // one memset over rp + wcur + psum (contiguous)
    size_t zero_ints = (size_t)(N_USER + 1) * 3 + (N_POST + 1)
                     + (size_t)N_USER * 3 + N_POST + 256;
    hipMemsetAsync(rp_re, 0, zero_ints * sizeof(int), stream);

    hist_all<<<2048, 256, 0, stream>>>(re_dst, E_re, rp_re,
                                       fb_dst, E_fb, rp_fb,
                                       soc_dst, E_soc, rp_soc,
                                       eng_dst, E_eng, rp_post);

    const int SC_BLOCKS_ALL = 3 * NBU + NBP;   // 124
    scan_partial_all<<<SC_BLOCKS_ALL, SCB, 0, stream>>>(rp_re, rp_fb, rp_soc,
                                                        rp_post, psum);
    scan_psum_all<<<4, 1024, 0, stream>>>(psum);
    scan_final_all<<<SC_BLOCKS_ALL, SCB, 0, stream>>>(rp_re, rp_fb, rp_soc,
                                                      rp_post, psum,
                                                      E_re, E_fb, E_soc, E_eng);

    fill_all<<<2048, 256, 0, stream>>>(
        re_src,  re_dst,  E_re,  rp_re,   wcur_re,   col_re,
        fb_src,  fb_dst,  E_fb,  rp_fb,   wcur_fb,   col_fb,
        soc_src, soc_dst, E_soc, rp_soc,  wcur_soc,  col_soc,
        eng_src, eng_dst, E_eng, rp_post, wcur_post, col_post);

    main_fused_kernel<<<GU + GP, 512, 0, stream>>>(
        x_user, x_post, rp_re, col_re, rp_fb, col_fb, rp_soc, col_soc,
        rp_post, col_post, Wl_d, Wl_a, Wl_s, Wr_d, Wr_a, Wr_s,
        bl_d, bl_a, bl_s, Wl_p, Wr_p, bl_p, out_user, out_post);
}